// Round 1
// baseline (519.553 us; speedup 1.0000x reference)
//
#include <hip/hip_runtime.h>
#include <hip/hip_bf16.h>

// MFMA fragment types (gfx950: __builtin_amdgcn_mfma_f32_16x16x32_bf16 takes v8bf16)
typedef __bf16 bf16x8 __attribute__((ext_vector_type(8)));
typedef __bf16 bf16x4 __attribute__((ext_vector_type(4)));
typedef float  f32x4  __attribute__((ext_vector_type(4)));

#define BT    2048
#define ANUM  128
#define VDIM  512
#define HDIM  512
#define MDIM  48
#define LDV   520   // padded LDS row stride (bf16 elems): 2-way-only bank aliasing

// ws byte offsets
#define WS_WVID  0
#define WS_WV    (512*512*2)
#define WS_INTER (WS_WV + 48*512*2)
// total ws use: 966,656 B

// ---------------------------------------------------------------- kernel 0
__global__ __launch_bounds__(256) void convert_weights(
    const float* __restrict__ Wvid, const float* __restrict__ Wv,
    __bf16* __restrict__ wvid_b, __bf16* __restrict__ wv_b) {
    int i = blockIdx.x * blockDim.x + threadIdx.x;
    const int nv = (512 * 512) / 4;   // float4 count for W_video
    const int n2 = (48 * 512) / 4;    // float4 count for W_v
    if (i < nv) {
        float4 f = ((const float4*)Wvid)[i];
        bf16x4 o = {(__bf16)f.x, (__bf16)f.y, (__bf16)f.z, (__bf16)f.w};
        ((bf16x4*)wvid_b)[i] = o;
    } else if (i < nv + n2) {
        int j = i - nv;
        float4 f = ((const float4*)Wv)[j];
        bf16x4 o = {(__bf16)f.x, (__bf16)f.y, (__bf16)f.z, (__bf16)f.w};
        ((bf16x4*)wv_b)[j] = o;
    }
}

// ---------------------------------------------------------------- kernel 1
// per-bt: a = relu(audio @ W_audio^T + b_audio) [512]; inter = a @ W_g^T [48]
__global__ __launch_bounds__(512) void audio_path(
    const float* __restrict__ audio, const float* __restrict__ Wa,
    const float* __restrict__ ba, const float* __restrict__ Wg,
    float* __restrict__ inter) {
    __shared__ float ain[ANUM];
    __shared__ float as[HDIM];
    const int bt = blockIdx.x;
    const int t  = threadIdx.x;

    if (t < ANUM) ain[t] = audio[bt * ANUM + t];
    __syncthreads();

    {   // a[t] over K=128
        float acc = ba[t];
        const float4* wr = (const float4*)(Wa + t * ANUM);
        #pragma unroll 8
        for (int k4 = 0; k4 < ANUM / 4; ++k4) {
            float4 wv = wr[k4];
            acc += ain[k4*4+0]*wv.x + ain[k4*4+1]*wv.y
                 + ain[k4*4+2]*wv.z + ain[k4*4+3]*wv.w;
        }
        as[t] = fmaxf(acc, 0.f);
    }
    __syncthreads();

    if (t < MDIM * 8) {  // 48 m's x 8 partial-threads
        int m = t >> 3, p = t & 7;
        const float4* wr = (const float4*)(Wg + m * HDIM + p * 64);
        float acc = 0.f;
        #pragma unroll
        for (int k4 = 0; k4 < 16; ++k4) {
            float4 wv = wr[k4];
            const float* a4 = &as[p * 64 + k4 * 4];
            acc += a4[0]*wv.x + a4[1]*wv.y + a4[2]*wv.z + a4[3]*wv.w;
        }
        acc += __shfl_xor(acc, 1);
        acc += __shfl_xor(acc, 2);
        acc += __shfl_xor(acc, 4);
        if (p == 0) inter[bt * MDIM + m] = acc;
    }
}

// ---------------------------------------------------------------- kernel 2
// per-bt fused: v-GEMM (bf16 MFMA) -> relu -> content GEMM -> tanh -> z
//               -> softmax -> c = alpha @ V (fp32 from global)
__global__ __launch_bounds__(512) void main_fused(
    const float* __restrict__ video, const float* __restrict__ bvid,
    const __bf16* __restrict__ wvid_b, const __bf16* __restrict__ wv_b,
    const float* __restrict__ Wh, const float* __restrict__ inter_g,
    float* __restrict__ out) {

    __shared__ __bf16 buf[MDIM][LDV];   // phase<=2: V bf16; phase>=3: vact bf16
    __shared__ float bias_s[HDIM];
    __shared__ float inter_s[MDIM];
    __shared__ float z_s[MDIM];
    __shared__ float alpha_s[MDIM];

    const int bt   = blockIdx.x;
    const int tid  = threadIdx.x;
    const int w    = tid >> 6;     // wave 0..7
    const int lane = tid & 63;
    const int l16  = lane & 15;
    const int quad = lane >> 4;

    const float* Vg = video + (size_t)bt * (MDIM * VDIM);

    // ---- phase 0: small preloads
    bias_s[tid] = bvid[tid];
    if (tid < MDIM) { inter_s[tid] = inter_g[bt * MDIM + tid]; z_s[tid] = 0.f; }

    // ---- phase 1: stage V (fp32 global) -> bf16 LDS, coalesced float4
    #pragma unroll
    for (int i = 0; i < 12; ++i) {
        int f   = tid + i * 512;        // float4 index, 6144 total
        int row = f >> 7;               // 128 float4 per row
        int c4  = f & 127;
        float4 v = ((const float4*)Vg)[f];
        bf16x4 o = {(__bf16)v.x, (__bf16)v.y, (__bf16)v.z, (__bf16)v.w};
        *(bf16x4*)&buf[row][c4 * 4] = o;
    }
    __syncthreads();

    // ---- phase 2: v = relu(V @ Wvid^T + b)  [48 x 512], this wave owns h in [64w, 64w+64)
    f32x4 acc[3][4];
    #pragma unroll
    for (int mt = 0; mt < 3; ++mt)
        #pragma unroll
        for (int j = 0; j < 4; ++j) {
            f32x4 z = {0.f, 0.f, 0.f, 0.f};
            acc[mt][j] = z;
        }
    const int h0 = w * 64;
    for (int kt = 0; kt < 16; ++kt) {
        bf16x8 a[3], b[4];
        #pragma unroll
        for (int mt = 0; mt < 3; ++mt)
            a[mt] = *(const bf16x8*)&buf[mt * 16 + l16][kt * 32 + quad * 8];
        #pragma unroll
        for (int j = 0; j < 4; ++j)
            b[j] = *(const bf16x8*)(wvid_b + (size_t)(h0 + j * 16 + l16) * VDIM
                                    + kt * 32 + quad * 8);
        #pragma unroll
        for (int mt = 0; mt < 3; ++mt)
            #pragma unroll
            for (int j = 0; j < 4; ++j)
                acc[mt][j] = __builtin_amdgcn_mfma_f32_16x16x32_bf16(
                                 a[mt], b[j], acc[mt][j], 0, 0, 0);
    }
    __syncthreads();   // everyone done READING buf (V)

    // epilogue: relu + bias, write vact into the same LDS buffer
    // D layout: row(s) = quad*4 + r (+16*mt), col(h) = l16 (+16*j + h0)
    #pragma unroll
    for (int mt = 0; mt < 3; ++mt)
        #pragma unroll
        for (int j = 0; j < 4; ++j) {
            int h = h0 + j * 16 + l16;
            float bias = bias_s[h];
            #pragma unroll
            for (int r = 0; r < 4; ++r) {
                int s = mt * 16 + quad * 4 + r;
                float val = fmaxf(acc[mt][j][r] + bias, 0.f);
                buf[s][h] = (__bf16)val;
            }
        }
    __syncthreads();

    // ---- phase 3: content[s][m] = vact @ Wv^T + inter[s]; z[s] += tanh(.)*Wh[m]
    // 9 tiles of 16x16 over K=512; one wave per tile (wave 0 takes 2)
    for (int t = w; t < 9; t += 8) {
        int ti = t / 3, tj = t % 3;
        f32x4 cacc = {0.f, 0.f, 0.f, 0.f};
        for (int kt = 0; kt < 16; ++kt) {
            bf16x8 a = *(const bf16x8*)&buf[ti * 16 + l16][kt * 32 + quad * 8];
            bf16x8 b = *(const bf16x8*)(wv_b + (size_t)(tj * 16 + l16) * HDIM
                                        + kt * 32 + quad * 8);
            cacc = __builtin_amdgcn_mfma_f32_16x16x32_bf16(a, b, cacc, 0, 0, 0);
        }
        int   mcol = tj * 16 + l16;
        float wh   = Wh[mcol];
        #pragma unroll
        for (int r = 0; r < 4; ++r) {
            int s = ti * 16 + quad * 4 + r;
            float cv = cacc[r] + inter_s[s];
            float contrib = tanhf(cv) * wh;
            contrib += __shfl_xor(contrib, 1);
            contrib += __shfl_xor(contrib, 2);
            contrib += __shfl_xor(contrib, 4);
            contrib += __shfl_xor(contrib, 8);
            if (l16 == 0) atomicAdd(&z_s[s], contrib);
        }
    }
    __syncthreads();

    // ---- phase 4: softmax over z[48] (wave 0)
    if (w == 0) {
        float x = (lane < MDIM) ? z_s[lane] : -INFINITY;
        float mx = x;
        #pragma unroll
        for (int off = 32; off >= 1; off >>= 1) mx = fmaxf(mx, __shfl_xor(mx, off));
        float e = (lane < MDIM) ? expf(x - mx) : 0.f;
        float sm = e;
        #pragma unroll
        for (int off = 32; off >= 1; off >>= 1) sm += __shfl_xor(sm, off);
        if (lane < MDIM) alpha_s[lane] = e / sm;
    }
    __syncthreads();

    // ---- phase 5: c[h] = sum_s alpha[s] * V[s][h]  (fp32 from global, L2-hot)
    float acc5 = 0.f;
    #pragma unroll 8
    for (int s = 0; s < MDIM; ++s)
        acc5 += alpha_s[s] * Vg[s * VDIM + tid];
    out[(size_t)bt * VDIM + tid] = acc5;
}

// ---------------------------------------------------------------- launch
extern "C" void kernel_launch(void* const* d_in, const int* in_sizes, int n_in,
                              void* d_out, int out_size, void* d_ws, size_t ws_size,
                              hipStream_t stream) {
    const float* audio   = (const float*)d_in[0];
    const float* video   = (const float*)d_in[1];
    const float* W_audio = (const float*)d_in[2];
    const float* b_audio = (const float*)d_in[3];
    const float* W_video = (const float*)d_in[4];
    const float* b_video = (const float*)d_in[5];
    const float* W_v     = (const float*)d_in[6];
    const float* W_g     = (const float*)d_in[7];
    const float* W_h     = (const float*)d_in[8];
    float* out = (float*)d_out;

    char* ws = (char*)d_ws;
    __bf16* wvid_b = (__bf16*)(ws + WS_WVID);
    __bf16* wv_b   = (__bf16*)(ws + WS_WV);
    float*  inter  = (float*)(ws + WS_INTER);

    convert_weights<<<280, 256, 0, stream>>>(W_video, W_v, wvid_b, wv_b);
    audio_path<<<BT, 512, 0, stream>>>(audio, W_audio, b_audio, W_g, inter);
    main_fused<<<BT, 512, 0, stream>>>(video, b_video, wvid_b, wv_b, W_h, inter, out);
}

// Round 2
// 503.305 us; speedup vs baseline: 1.0323x; 1.0323x over previous
//
#include <hip/hip_runtime.h>
#include <hip/hip_bf16.h>

typedef __bf16 bf16x8 __attribute__((ext_vector_type(8)));
typedef __bf16 bf16x4 __attribute__((ext_vector_type(4)));
typedef float  f32x4  __attribute__((ext_vector_type(4)));

#define BT    2048
#define MDIM  48

// ws byte offsets (total 1,015,808 B)
#define WS_WVID  0
#define WS_WV    (512*512*2)            // 524288
#define WS_WG    (WS_WV + 48*512*2)     // 573440
#define WS_INTER (WS_WG + 48*512*2)     // 622592

// ---------------------------------------------------------------- kernel 0
// fp32 -> bf16 conversion of W_video, W_v, W_g. Grid covers exactly 77824 f4.
__global__ __launch_bounds__(256) void convert_weights(
    const float* __restrict__ Wvid, const float* __restrict__ Wv,
    const float* __restrict__ Wg,
    __bf16* __restrict__ wvid_b, __bf16* __restrict__ wv_b,
    __bf16* __restrict__ wg_b) {
    int i = blockIdx.x * blockDim.x + threadIdx.x;
    const int nv = 65536, n2 = 6144;
    const float4* src; bf16x4* dst; int j;
    if (i < nv)           { src = (const float4*)Wvid; dst = (bf16x4*)wvid_b; j = i; }
    else if (i < nv + n2) { src = (const float4*)Wv;   dst = (bf16x4*)wv_b;   j = i - nv; }
    else                  { src = (const float4*)Wg;   dst = (bf16x4*)wg_b;   j = i - nv - n2; }
    float4 f = src[j];
    bf16x4 o = {(__bf16)f.x, (__bf16)f.y, (__bf16)f.z, (__bf16)f.w};
    dst[j] = o;
}

// ---------------------------------------------------------------- kernel 1
// batched audio path: 16 bt per block, 128 blocks.
// a = relu(audio @ Wa^T + ba) [16x512] -> LDS bf16 swizzled -> inter = a @ Wg^T via MFMA.
__global__ __launch_bounds__(512) void audio_batch(
    const float* __restrict__ audio, const float* __restrict__ Wa,
    const float* __restrict__ ba, const __bf16* __restrict__ wg_b,
    float* __restrict__ inter) {
    __shared__ float  ain[16 * 128];        // 8 KB
    __shared__ __bf16 as_s[64 * 17 * 8];    // 17408 B, granule-swizzled (pad 16->17)

    const int bt0 = blockIdx.x * 16;
    const int t   = threadIdx.x;

    // stage audio[16][128] coalesced (512 float4 = exactly one per thread)
    ((float4*)ain)[t] = ((const float4*)(audio + (size_t)bt0 * 128))[t];
    __syncthreads();

    // thread t owns hidden unit h = t, all 16 bt
    float acc[16];
    float bias = ba[t];
    #pragma unroll
    for (int b = 0; b < 16; ++b) acc[b] = bias;
    const float4* wr = (const float4*)(Wa + (size_t)t * 128);
    #pragma unroll 4
    for (int k4 = 0; k4 < 32; ++k4) {
        float4 wv = wr[k4];
        #pragma unroll
        for (int b = 0; b < 16; ++b) {
            float4 av = ((const float4*)ain)[b * 32 + k4];  // LDS broadcast
            acc[b] += av.x*wv.x + av.y*wv.y + av.z*wv.z + av.w*wv.w;
        }
    }
    // relu + store swizzled bf16: elem((h8=t>>3)*17 + bt)*8 + (t&7)
    #pragma unroll
    for (int b = 0; b < 16; ++b)
        as_s[(((t >> 3) * 17 + b) << 3) | (t & 7)] = (__bf16)fmaxf(acc[b], 0.f);
    __syncthreads();

    // inter GEMM: M=16(bt), N=48(m) in 3 tiles, K=512. Waves 0..2.
    const int w = t >> 6, lane = t & 63, l16 = lane & 15, quad = lane >> 4;
    if (w < 3) {
        f32x4 c = {0.f, 0.f, 0.f, 0.f};
        const __bf16* bp = wg_b + (size_t)(w * 16 + l16) * 512 + quad * 8;
        const __bf16* ap = &as_s[((quad * 17 + l16)) * 8];
        bf16x8 aC = *(const bf16x8*)ap;
        bf16x8 bC = *(const bf16x8*)bp;
        #pragma unroll
        for (int kt = 0; kt < 16; ++kt) {
            bf16x8 aN, bN;
            if (kt < 15) {
                aN = *(const bf16x8*)(ap + (kt + 1) * (4 * 17 * 8));
                bN = *(const bf16x8*)(bp + (kt + 1) * 32);
            }
            c = __builtin_amdgcn_mfma_f32_16x16x32_bf16(aC, bC, c, 0, 0, 0);
            if (kt < 15) { aC = aN; bC = bN; }
        }
        // D: row(bt) = quad*4+r, col(m) = l16
        #pragma unroll
        for (int r = 0; r < 4; ++r)
            inter[(size_t)(bt0 + quad * 4 + r) * 48 + w * 16 + l16] = c[r];
    }
}

// ---------------------------------------------------------------- kernel 2
// per-bt fused: v-GEMM (MFMA, pipelined) -> relu -> content GEMM -> tanh -> z
//               -> softmax -> c = alpha @ V
// LDS buf granule-swizzle: 16B granule (col8, row) at 16B-index col8*49 + row.
__global__ __launch_bounds__(512) void main_fused(
    const float* __restrict__ video, const float* __restrict__ bvid,
    const __bf16* __restrict__ wvid_b, const __bf16* __restrict__ wv_b,
    const float* __restrict__ Wh, const float* __restrict__ inter_g,
    float* __restrict__ out) {

    __shared__ __bf16 buf[64 * 49 * 8];   // 50176 B; phase<=2: V, phase>=3: vact
    __shared__ float bias_s[512];
    __shared__ float inter_s[MDIM];
    __shared__ float z_s[MDIM];
    __shared__ float alpha_s[MDIM];
    __shared__ float content8[256];       // tile-8 partial accumulator

    const int bt   = blockIdx.x;
    const int tid  = threadIdx.x;
    const int w    = tid >> 6;
    const int lane = tid & 63;
    const int l16  = lane & 15;
    const int quad = lane >> 4;

    const float* Vg = video + (size_t)bt * (48 * 512);

    // ---- phase 0
    bias_s[tid] = bvid[tid];
    if (tid < MDIM) { inter_s[tid] = inter_g[bt * MDIM + tid]; z_s[tid] = 0.f; }
    if (tid < 256) content8[tid] = 0.f;

    // ---- phase 1: V fp32 -> bf16 LDS (swizzled), coalesced 32B/lane
    #pragma unroll
    for (int p = 0; p < 6; ++p) {
        int idx  = tid + p * 512;       // 3072 granules
        int row  = idx >> 6;            // 0..47
        int col8 = idx & 63;            // 0..63
        const float4* s4 = (const float4*)Vg + row * 128 + col8 * 2;
        float4 x = s4[0], y = s4[1];
        bf16x8 g = {(__bf16)x.x, (__bf16)x.y, (__bf16)x.z, (__bf16)x.w,
                    (__bf16)y.x, (__bf16)y.y, (__bf16)y.z, (__bf16)y.w};
        *(bf16x8*)&buf[(col8 * 49 + row) * 8] = g;
    }
    __syncthreads();

    // ---- phase 2: v = relu(V @ Wvid^T + b); wave w owns h in [64w, 64w+64)
    f32x4 acc[3][4];
    #pragma unroll
    for (int mt = 0; mt < 3; ++mt)
        #pragma unroll
        for (int j = 0; j < 4; ++j) {
            f32x4 z = {0.f, 0.f, 0.f, 0.f};
            acc[mt][j] = z;
        }
    {
        const __bf16* aptr = &buf[(quad * 49 + l16) * 8];
        const __bf16* bptr = wvid_b + (size_t)(w * 64 + l16) * 512 + quad * 8;

        bf16x8 aC[3], bC[4];
        #pragma unroll
        for (int mt = 0; mt < 3; ++mt) aC[mt] = *(const bf16x8*)(aptr + mt * 128);
        #pragma unroll
        for (int j = 0; j < 4; ++j)    bC[j]  = *(const bf16x8*)(bptr + j * 8192);

        #pragma unroll
        for (int kt = 0; kt < 16; ++kt) {
            bf16x8 aN[3], bN[4];
            if (kt < 15) {
                #pragma unroll
                for (int mt = 0; mt < 3; ++mt)
                    aN[mt] = *(const bf16x8*)(aptr + (kt + 1) * 1568 + mt * 128);
                #pragma unroll
                for (int j = 0; j < 4; ++j)
                    bN[j] = *(const bf16x8*)(bptr + j * 8192 + (kt + 1) * 32);
            }
            #pragma unroll
            for (int mt = 0; mt < 3; ++mt)
                #pragma unroll
                for (int j = 0; j < 4; ++j)
                    acc[mt][j] = __builtin_amdgcn_mfma_f32_16x16x32_bf16(
                                     aC[mt], bC[j], acc[mt][j], 0, 0, 0);
            if (kt < 15) {
                #pragma unroll
                for (int mt = 0; mt < 3; ++mt) aC[mt] = aN[mt];
                #pragma unroll
                for (int j = 0; j < 4; ++j)    bC[j]  = bN[j];
            }
        }
    }
    __syncthreads();   // all waves done reading buf(V)

    // epilogue: relu+bias, write vact into buf (swizzled). D: row(s)=quad*4+r, col(h)=l16
    #pragma unroll
    for (int mt = 0; mt < 3; ++mt)
        #pragma unroll
        for (int j = 0; j < 4; ++j) {
            int h = w * 64 + j * 16 + l16;
            float bias = bias_s[h];
            int g = (h >> 3) * 49, e = h & 7;
            #pragma unroll
            for (int r = 0; r < 4; ++r) {
                int s = mt * 16 + quad * 4 + r;
                buf[(g + s) * 8 + e] = (__bf16)fmaxf(acc[mt][j][r] + bias, 0.f);
            }
        }
    __syncthreads();

    // ---- phase 3: content = vact @ Wv^T + inter; z[s] += tanh(.)*Wh[m]
    // tiles 0..7 -> wave w; tile 8 (ti=2,tj=2) split: wave w does kt=2w,2w+1.
    {
        int ti = w / 3, tj = w - ti * 3;
        const __bf16* bp = wv_b + (size_t)(tj * 16 + l16) * 512 + quad * 8;
        const __bf16* ap = &buf[(quad * 49 + ti * 16 + l16) * 8];
        f32x4 c3 = {0.f, 0.f, 0.f, 0.f};
        bf16x8 aC = *(const bf16x8*)ap;
        bf16x8 bC = *(const bf16x8*)bp;
        #pragma unroll
        for (int kt = 0; kt < 16; ++kt) {
            bf16x8 aN, bN;
            if (kt < 15) {
                aN = *(const bf16x8*)(ap + (kt + 1) * 1568);
                bN = *(const bf16x8*)(bp + (kt + 1) * 32);
            }
            c3 = __builtin_amdgcn_mfma_f32_16x16x32_bf16(aC, bC, c3, 0, 0, 0);
            if (kt < 15) { aC = aN; bC = bN; }
        }
        int   mcol = tj * 16 + l16;
        float wh   = Wh[mcol];
        #pragma unroll
        for (int r = 0; r < 4; ++r) {
            int s = ti * 16 + quad * 4 + r;
            float contrib = tanhf(c3[r] + inter_s[s]) * wh;
            contrib += __shfl_xor(contrib, 1);
            contrib += __shfl_xor(contrib, 2);
            contrib += __shfl_xor(contrib, 4);
            contrib += __shfl_xor(contrib, 8);
            if (l16 == 0) atomicAdd(&z_s[s], contrib);
        }
        // tile 8 slice: 2 MFMAs per wave
        f32x4 p8 = {0.f, 0.f, 0.f, 0.f};
        #pragma unroll
        for (int q = 0; q < 2; ++q) {
            int kt = 2 * w + q;
            bf16x8 a8 = *(const bf16x8*)&buf[((kt * 4 + quad) * 49 + 32 + l16) * 8];
            bf16x8 b8 = *(const bf16x8*)(wv_b + (size_t)(32 + l16) * 512 + kt * 32 + quad * 8);
            p8 = __builtin_amdgcn_mfma_f32_16x16x32_bf16(a8, b8, p8, 0, 0, 0);
        }
        #pragma unroll
        for (int r = 0; r < 4; ++r)
            atomicAdd(&content8[(quad * 4 + r) * 16 + l16], p8[r]);
    }
    __syncthreads();

    // tile-8 finalize (wave 0 only)
    if (w == 0) {
        float wh = Wh[32 + l16];
        #pragma unroll
        for (int r = 0; r < 4; ++r) {
            int s = 32 + quad * 4 + r;
            float contrib = tanhf(content8[(quad * 4 + r) * 16 + l16] + inter_s[s]) * wh;
            contrib += __shfl_xor(contrib, 1);
            contrib += __shfl_xor(contrib, 2);
            contrib += __shfl_xor(contrib, 4);
            contrib += __shfl_xor(contrib, 8);
            if (l16 == 0) atomicAdd(&z_s[s], contrib);
        }
    }
    __syncthreads();

    // ---- phase 4: softmax over z[48] (wave 0)
    if (w == 0) {
        float x = (lane < MDIM) ? z_s[lane] : -INFINITY;
        float mx = x;
        #pragma unroll
        for (int off = 32; off >= 1; off >>= 1) mx = fmaxf(mx, __shfl_xor(mx, off));
        float e = (lane < MDIM) ? expf(x - mx) : 0.f;
        float sm = e;
        #pragma unroll
        for (int off = 32; off >= 1; off >>= 1) sm += __shfl_xor(sm, off);
        if (lane < MDIM) alpha_s[lane] = e / sm;
    }
    __syncthreads();

    // ---- phase 5: c[h] = sum_s alpha[s] * V[s][h] (fp32 global, L2/L3-hot)
    float acc5 = 0.f;
    #pragma unroll
    for (int s = 0; s < MDIM; ++s)
        acc5 += alpha_s[s] * Vg[s * 512 + tid];
    out[(size_t)bt * 512 + tid] = acc5;
}

// ---------------------------------------------------------------- launch
extern "C" void kernel_launch(void* const* d_in, const int* in_sizes, int n_in,
                              void* d_out, int out_size, void* d_ws, size_t ws_size,
                              hipStream_t stream) {
    const float* audio   = (const float*)d_in[0];
    const float* video   = (const float*)d_in[1];
    const float* W_audio = (const float*)d_in[2];
    const float* b_audio = (const float*)d_in[3];
    const float* W_video = (const float*)d_in[4];
    const float* b_video = (const float*)d_in[5];
    const float* W_v     = (const float*)d_in[6];
    const float* W_g     = (const float*)d_in[7];
    const float* W_h     = (const float*)d_in[8];
    float* out = (float*)d_out;

    char* ws = (char*)d_ws;
    __bf16* wvid_b = (__bf16*)(ws + WS_WVID);
    __bf16* wv_b   = (__bf16*)(ws + WS_WV);
    __bf16* wg_b   = (__bf16*)(ws + WS_WG);
    float*  inter  = (float*)(ws + WS_INTER);

    convert_weights<<<304, 256, 0, stream>>>(W_video, W_v, W_g, wvid_b, wv_b, wg_b);
    audio_batch<<<BT / 16, 512, 0, stream>>>(audio, W_audio, b_audio, wg_b, inter);
    main_fused<<<BT, 512, 0, stream>>>(video, b_video, wvid_b, wv_b, W_h, inter, out);
}

// Round 3
// 429.628 us; speedup vs baseline: 1.2093x; 1.1715x over previous
//
#include <hip/hip_runtime.h>
#include <hip/hip_bf16.h>

typedef __bf16 bf16x8 __attribute__((ext_vector_type(8)));
typedef __bf16 bf16x4 __attribute__((ext_vector_type(4)));
typedef float  f32x4  __attribute__((ext_vector_type(4)));

#define BT    2048
#define MDIM  48

// ws byte offsets
#define WS_WVID  0
#define WS_WV    (512*512*2)
#define WS_WG    (WS_WV + 48*512*2)
#define WS_INTER (WS_WG + 48*512*2)

// LDS pool layout (bytes). Phase 2: B dbuf 2x32KB @0, A dbuf 2x3840B @65536.
// Phase >=3: vact 48 rows x 1040 B @0 (aliased; barriers separate uses).
#define POOL_BYTES 73216
#define B_OFF(b)   ((b) * 32768)
#define A_OFF(b)   (65536 + (b) * 3840)

__device__ __forceinline__ void gload_lds16(const void* g, void* l) {
    __builtin_amdgcn_global_load_lds(
        (const __attribute__((address_space(1))) unsigned int*)g,
        (__attribute__((address_space(3))) unsigned int*)l,
        16, 0, 0);
}

// ---------------------------------------------------------------- kernel 0
__global__ __launch_bounds__(256) void convert_weights(
    const float* __restrict__ Wvid, const float* __restrict__ Wv,
    const float* __restrict__ Wg,
    __bf16* __restrict__ wvid_b, __bf16* __restrict__ wv_b,
    __bf16* __restrict__ wg_b) {
    int i = blockIdx.x * blockDim.x + threadIdx.x;
    const int nv = 65536, n2 = 6144;
    const float4* src; bf16x4* dst; int j;
    if (i < nv)           { src = (const float4*)Wvid; dst = (bf16x4*)wvid_b; j = i; }
    else if (i < nv + n2) { src = (const float4*)Wv;   dst = (bf16x4*)wv_b;   j = i - nv; }
    else                  { src = (const float4*)Wg;   dst = (bf16x4*)wg_b;   j = i - nv - n2; }
    float4 f = src[j];
    bf16x4 o = {(__bf16)f.x, (__bf16)f.y, (__bf16)f.z, (__bf16)f.w};
    dst[j] = o;
}

// ---------------------------------------------------------------- kernel 1
__global__ __launch_bounds__(512) void audio_batch(
    const float* __restrict__ audio, const float* __restrict__ Wa,
    const float* __restrict__ ba, const __bf16* __restrict__ wg_b,
    float* __restrict__ inter) {
    __shared__ float  ain[16 * 128];
    __shared__ __bf16 as_s[64 * 17 * 8];

    const int bt0 = blockIdx.x * 16;
    const int t   = threadIdx.x;

    ((float4*)ain)[t] = ((const float4*)(audio + (size_t)bt0 * 128))[t];
    __syncthreads();

    float acc[16];
    float bias = ba[t];
    #pragma unroll
    for (int b = 0; b < 16; ++b) acc[b] = bias;
    const float4* wr = (const float4*)(Wa + (size_t)t * 128);
    #pragma unroll 4
    for (int k4 = 0; k4 < 32; ++k4) {
        float4 wv = wr[k4];
        #pragma unroll
        for (int b = 0; b < 16; ++b) {
            float4 av = ((const float4*)ain)[b * 32 + k4];
            acc[b] += av.x*wv.x + av.y*wv.y + av.z*wv.z + av.w*wv.w;
        }
    }
    #pragma unroll
    for (int b = 0; b < 16; ++b)
        as_s[(((t >> 3) * 17 + b) << 3) | (t & 7)] = (__bf16)fmaxf(acc[b], 0.f);
    __syncthreads();

    const int w = t >> 6, lane = t & 63, l16 = lane & 15, quad = lane >> 4;
    if (w < 3) {
        f32x4 c = {0.f, 0.f, 0.f, 0.f};
        const __bf16* bp = wg_b + (size_t)(w * 16 + l16) * 512 + quad * 8;
        const __bf16* ap = &as_s[((quad * 17 + l16)) * 8];
        bf16x8 aC = *(const bf16x8*)ap;
        bf16x8 bC = *(const bf16x8*)bp;
        #pragma unroll
        for (int kt = 0; kt < 16; ++kt) {
            bf16x8 aN, bN;
            if (kt < 15) {
                aN = *(const bf16x8*)(ap + (kt + 1) * (4 * 17 * 8));
                bN = *(const bf16x8*)(bp + (kt + 1) * 32);
            }
            c = __builtin_amdgcn_mfma_f32_16x16x32_bf16(aC, bC, c, 0, 0, 0);
            if (kt < 15) { aC = aN; bC = bN; }
        }
        #pragma unroll
        for (int r = 0; r < 4; ++r)
            inter[(size_t)(bt0 + quad * 4 + r) * 48 + w * 16 + l16] = c[r];
    }
}

// ---------------------------------------------------------------- kernel 2
// per-bt fused, async-staged K-loop:
//   per kt: barrier; issue A-reg load + B global_load_lds for kt+1; MFMA on kt;
//   cvt+ds_write A(kt+1). B granule-swizzled ((quad+h)&3); A rows padded 80 B.
__global__ __launch_bounds__(512) void main_fused(
    const float* __restrict__ video, const float* __restrict__ bvid,
    const __bf16* __restrict__ wvid_b, const __bf16* __restrict__ wv_b,
    const float* __restrict__ Wh, const float* __restrict__ inter_g,
    float* __restrict__ out) {

    __shared__ uint4 pool4[POOL_BYTES / 16];
    __shared__ float bias_s[512];
    __shared__ float inter_s[MDIM];
    __shared__ float z_s[MDIM];
    __shared__ float alpha_s[MDIM];
    __shared__ float content8[256];

    char* pool = (char*)pool4;

    const int bt   = blockIdx.x;
    const int tid  = threadIdx.x;
    const int w    = tid >> 6;
    const int lane = tid & 63;
    const int l16  = lane & 15;
    const int quad = lane >> 4;

    const float* Vg = video + (size_t)bt * (48 * 512);
    const char*  wvid_bytes = (const char*)wvid_b;

    // ---- phase 0: small preloads
    bias_s[tid] = bvid[tid];
    if (tid < MDIM) { inter_s[tid] = inter_g[bt * MDIM + tid]; z_s[tid] = 0.f; }
    if (tid < 256) content8[tid] = 0.f;

    // ---- B staging per-lane global byte offsets (q = 0..3)
    int gq[4];
    #pragma unroll
    for (int q = 0; q < 4; ++q) {
        int g  = (w * 4 + q) * 64 + lane;   // LDS granule index
        int h  = g >> 2;
        int k8 = ((g & 3) - h) & 3;         // stored swizzle: (k8 + h) & 3 == g&3
        gq[q] = h * 1024 + k8 * 16;         // bytes into wvid_b (+ kt*64 per slice)
    }
    // A staging ownership: threads 0..383 cover 48 rows x 8 float4
    const bool aOwn = tid < 384;
    const int  am = tid >> 3, ak4 = tid & 7;
    const float4* aSrc = (const float4*)(Vg + am * 512) + ak4;

    // frag read byte offsets
    const int aRd = l16 * 80 + quad * 16;                       // + mt*1280 + A_OFF
    const int bRd = (w * 64 + l16) * 64 + ((quad + l16) & 3) * 16;  // + j*1024 + B_OFF

    // ---- prologue: stage slice 0 into buffer 0
    #pragma unroll
    for (int q = 0; q < 4; ++q)
        gload_lds16(wvid_bytes + gq[q], pool + B_OFF(0) + (w * 4 + q) * 1024);
    if (aOwn) {
        float4 av = aSrc[0];
        bf16x4 o = {(__bf16)av.x, (__bf16)av.y, (__bf16)av.z, (__bf16)av.w};
        *(bf16x4*)(pool + A_OFF(0) + am * 80 + ak4 * 8) = o;
    }

    // ---- phase 2 K-loop
    f32x4 acc[3][4];
    #pragma unroll
    for (int mt = 0; mt < 3; ++mt)
        #pragma unroll
        for (int j = 0; j < 4; ++j) {
            f32x4 z = {0.f, 0.f, 0.f, 0.f};
            acc[mt][j] = z;
        }

    for (int kt = 0; kt < 16; ++kt) {
        __syncthreads();                    // buffer kt&1 staged & prior reads done
        const int cb = kt & 1, nb = cb ^ 1;

        float4 av;
        if (kt < 15) {
            if (aOwn) av = aSrc[(kt + 1) * 8];   // issued first -> older vmcnt slot
            #pragma unroll
            for (int q = 0; q < 4; ++q)
                gload_lds16(wvid_bytes + gq[q] + (kt + 1) * 64,
                            pool + B_OFF(nb) + (w * 4 + q) * 1024);
        }

        bf16x8 aC[3], bC[4];
        #pragma unroll
        for (int mt = 0; mt < 3; ++mt)
            aC[mt] = *(const bf16x8*)(pool + A_OFF(cb) + aRd + mt * 1280);
        #pragma unroll
        for (int j = 0; j < 4; ++j)
            bC[j] = *(const bf16x8*)(pool + B_OFF(cb) + bRd + j * 1024);

        #pragma unroll
        for (int mt = 0; mt < 3; ++mt)
            #pragma unroll
            for (int j = 0; j < 4; ++j)
                acc[mt][j] = __builtin_amdgcn_mfma_f32_16x16x32_bf16(
                                 aC[mt], bC[j], acc[mt][j], 0, 0, 0);

        if (kt < 15 && aOwn) {
            bf16x4 o = {(__bf16)av.x, (__bf16)av.y, (__bf16)av.z, (__bf16)av.w};
            *(bf16x4*)(pool + A_OFF(nb) + am * 80 + ak4 * 8) = o;
        }
    }
    __syncthreads();    // all frag reads done; pool free for vact

    // epilogue: relu+bias -> vact rows of 1040 B. D: row(s)=quad*4+r, col(h)=l16
    #pragma unroll
    for (int mt = 0; mt < 3; ++mt)
        #pragma unroll
        for (int j = 0; j < 4; ++j) {
            int h = w * 64 + j * 16 + l16;
            float bias = bias_s[h];
            #pragma unroll
            for (int r = 0; r < 4; ++r) {
                int s = mt * 16 + quad * 4 + r;
                *(__bf16*)(pool + s * 1040 + h * 2) =
                    (__bf16)fmaxf(acc[mt][j][r] + bias, 0.f);
            }
        }
    __syncthreads();

    // ---- phase 3: content = vact @ Wv^T + inter; z[s] += tanh(.)*Wh[m]
    {
        int ti = w / 3, tj = w - ti * 3;    // tiles 0..7; tile 8 split below
        const __bf16* bp = wv_b + (size_t)(tj * 16 + l16) * 512 + quad * 8;
        const char*   ap = pool + (ti * 16 + l16) * 1040 + quad * 16;
        f32x4 c3 = {0.f, 0.f, 0.f, 0.f};
        bf16x8 aC = *(const bf16x8*)ap;
        bf16x8 bC = *(const bf16x8*)bp;
        #pragma unroll
        for (int kt = 0; kt < 16; ++kt) {
            bf16x8 aN, bN;
            if (kt < 15) {
                aN = *(const bf16x8*)(ap + (kt + 1) * 64);
                bN = *(const bf16x8*)(bp + (kt + 1) * 32);
            }
            c3 = __builtin_amdgcn_mfma_f32_16x16x32_bf16(aC, bC, c3, 0, 0, 0);
            if (kt < 15) { aC = aN; bC = bN; }
        }
        float wh = Wh[tj * 16 + l16];
        #pragma unroll
        for (int r = 0; r < 4; ++r) {
            int s = ti * 16 + quad * 4 + r;
            float contrib = tanhf(c3[r] + inter_s[s]) * wh;
            contrib += __shfl_xor(contrib, 1);
            contrib += __shfl_xor(contrib, 2);
            contrib += __shfl_xor(contrib, 4);
            contrib += __shfl_xor(contrib, 8);
            if (l16 == 0) atomicAdd(&z_s[s], contrib);
        }
        // tile 8 (ti=2,tj=2): wave w does kt = 2w, 2w+1
        f32x4 p8 = {0.f, 0.f, 0.f, 0.f};
        #pragma unroll
        for (int q = 0; q < 2; ++q) {
            int kt = 2 * w + q;
            bf16x8 a8 = *(const bf16x8*)(pool + (32 + l16) * 1040 + kt * 64 + quad * 16);
            bf16x8 b8 = *(const bf16x8*)(wv_b + (size_t)(32 + l16) * 512 + kt * 32 + quad * 8);
            p8 = __builtin_amdgcn_mfma_f32_16x16x32_bf16(a8, b8, p8, 0, 0, 0);
        }
        #pragma unroll
        for (int r = 0; r < 4; ++r)
            atomicAdd(&content8[(quad * 4 + r) * 16 + l16], p8[r]);
    }
    __syncthreads();

    if (w == 0) {
        float wh = Wh[32 + l16];
        #pragma unroll
        for (int r = 0; r < 4; ++r) {
            int s = 32 + quad * 4 + r;
            float contrib = tanhf(content8[(quad * 4 + r) * 16 + l16] + inter_s[s]) * wh;
            contrib += __shfl_xor(contrib, 1);
            contrib += __shfl_xor(contrib, 2);
            contrib += __shfl_xor(contrib, 4);
            contrib += __shfl_xor(contrib, 8);
            if (l16 == 0) atomicAdd(&z_s[s], contrib);
        }
    }
    __syncthreads();

    // ---- phase 4: softmax over z[48] (wave 0)
    if (w == 0) {
        float x = (lane < MDIM) ? z_s[lane] : -INFINITY;
        float mx = x;
        #pragma unroll
        for (int off = 32; off >= 1; off >>= 1) mx = fmaxf(mx, __shfl_xor(mx, off));
        float e = (lane < MDIM) ? expf(x - mx) : 0.f;
        float sm = e;
        #pragma unroll
        for (int off = 32; off >= 1; off >>= 1) sm += __shfl_xor(sm, off);
        if (lane < MDIM) alpha_s[lane] = e / sm;
    }
    __syncthreads();

    // ---- phase 5: c[h] = sum_s alpha[s] * V[s][h] (fp32 global, L2/L3-hot)
    float acc5 = 0.f;
    #pragma unroll
    for (int s = 0; s < MDIM; ++s)
        acc5 += alpha_s[s] * Vg[s * 512 + tid];
    out[(size_t)bt * 512 + tid] = acc5;
}

// ---------------------------------------------------------------- launch
extern "C" void kernel_launch(void* const* d_in, const int* in_sizes, int n_in,
                              void* d_out, int out_size, void* d_ws, size_t ws_size,
                              hipStream_t stream) {
    const float* audio   = (const float*)d_in[0];
    const float* video   = (const float*)d_in[1];
    const float* W_audio = (const float*)d_in[2];
    const float* b_audio = (const float*)d_in[3];
    const float* W_video = (const float*)d_in[4];
    const float* b_video = (const float*)d_in[5];
    const float* W_v     = (const float*)d_in[6];
    const float* W_g     = (const float*)d_in[7];
    const float* W_h     = (const float*)d_in[8];
    float* out = (float*)d_out;

    char* ws = (char*)d_ws;
    __bf16* wvid_b = (__bf16*)(ws + WS_WVID);
    __bf16* wv_b   = (__bf16*)(ws + WS_WV);
    __bf16* wg_b   = (__bf16*)(ws + WS_WG);
    float*  inter  = (float*)(ws + WS_INTER);

    convert_weights<<<304, 256, 0, stream>>>(W_video, W_v, W_g, wvid_b, wv_b, wg_b);
    audio_batch<<<BT / 16, 512, 0, stream>>>(audio, W_audio, b_audio, wg_b, inter);
    main_fused<<<BT, 512, 0, stream>>>(video, b_video, wvid_b, wv_b, W_h, inter, out);
}

// Round 5
// 399.037 us; speedup vs baseline: 1.3020x; 1.0767x over previous
//
#include <hip/hip_runtime.h>
#include <hip/hip_bf16.h>

typedef __bf16 bf16x8 __attribute__((ext_vector_type(8)));
typedef __bf16 bf16x4 __attribute__((ext_vector_type(4)));
typedef float  f32x4  __attribute__((ext_vector_type(4)));

#define BT    2048
#define MDIM  48

// ws byte offsets
#define WS_WVID  0                       // K-major granule layout, 512 KB
#define WS_WV    (512*512*2)
#define WS_WG    (WS_WV + 48*512*2)
#define WS_INTER (WS_WG + 48*512*2)

// ---------------------------------------------------------------- kernel 0
// W_video [512h x 512k] row-major fp32 -> K-major granule bf16:
// granule (kc,h), kc=0..63, at flat16 = kc*512 + h, holds W_video[h][kc*8..kc*8+7].
// W_v / W_g stay row-major bf16.
__global__ __launch_bounds__(256) void convert_weights(
    const float* __restrict__ Wvid, const float* __restrict__ Wv,
    const float* __restrict__ Wg,
    __bf16* __restrict__ wvid_k, __bf16* __restrict__ wv_b,
    __bf16* __restrict__ wg_b) {
    int i = blockIdx.x * blockDim.x + threadIdx.x;
    const int nv = 65536, n2 = 6144;
    if (i < nv) {
        int h = i >> 7, k4 = i & 127;    // 128 float4 per 512-elem row
        float4 f = ((const float4*)Wvid)[i];
        bf16x4 o = {(__bf16)f.x, (__bf16)f.y, (__bf16)f.z, (__bf16)f.w};
        *(bf16x4*)(wvid_k + (size_t)(((k4 >> 1) * 512 + h) * 8 + (k4 & 1) * 4)) = o;
    } else if (i < nv + n2) {
        int j = i - nv;
        float4 f = ((const float4*)Wv)[j];
        bf16x4 o = {(__bf16)f.x, (__bf16)f.y, (__bf16)f.z, (__bf16)f.w};
        ((bf16x4*)wv_b)[j] = o;
    } else {
        int j = i - nv - n2;
        float4 f = ((const float4*)Wg)[j];
        bf16x4 o = {(__bf16)f.x, (__bf16)f.y, (__bf16)f.z, (__bf16)f.w};
        ((bf16x4*)wg_b)[j] = o;
    }
}

// ---------------------------------------------------------------- kernel 1
__global__ __launch_bounds__(512) void audio_batch(
    const float* __restrict__ audio, const float* __restrict__ Wa,
    const float* __restrict__ ba, const __bf16* __restrict__ wg_b,
    float* __restrict__ inter) {
    __shared__ float  ain[16 * 128];
    __shared__ __bf16 as_s[64 * 17 * 8];

    const int bt0 = blockIdx.x * 16;
    const int t   = threadIdx.x;

    ((float4*)ain)[t] = ((const float4*)(audio + (size_t)bt0 * 128))[t];
    __syncthreads();

    float acc[16];
    float bias = ba[t];
    #pragma unroll
    for (int b = 0; b < 16; ++b) acc[b] = bias;
    const float4* wr = (const float4*)(Wa + (size_t)t * 128);
    #pragma unroll 4
    for (int k4 = 0; k4 < 32; ++k4) {
        float4 wv = wr[k4];
        #pragma unroll
        for (int b = 0; b < 16; ++b) {
            float4 av = ((const float4*)ain)[b * 32 + k4];
            acc[b] += av.x*wv.x + av.y*wv.y + av.z*wv.z + av.w*wv.w;
        }
    }
    #pragma unroll
    for (int b = 0; b < 16; ++b)
        as_s[(((t >> 3) * 17 + b) << 3) | (t & 7)] = (__bf16)fmaxf(acc[b], 0.f);
    __syncthreads();

    const int w = t >> 6, lane = t & 63, l16 = lane & 15, quad = lane >> 4;
    if (w < 3) {
        f32x4 c = {0.f, 0.f, 0.f, 0.f};
        const __bf16* bp = wg_b + (size_t)(w * 16 + l16) * 512 + quad * 8;
        const __bf16* ap = &as_s[((quad * 17 + l16)) * 8];
        bf16x8 aC = *(const bf16x8*)ap;
        bf16x8 bC = *(const bf16x8*)bp;
        #pragma unroll
        for (int kt = 0; kt < 16; ++kt) {
            bf16x8 aN, bN;
            if (kt < 15) {
                aN = *(const bf16x8*)(ap + (kt + 1) * (4 * 17 * 8));
                bN = *(const bf16x8*)(bp + (kt + 1) * 32);
            }
            c = __builtin_amdgcn_mfma_f32_16x16x32_bf16(aC, bC, c, 0, 0, 0);
            if (kt < 15) { aC = aN; bC = bN; }
        }
        #pragma unroll
        for (int r = 0; r < 4; ++r)
            inter[(size_t)(bt0 + quad * 4 + r) * 48 + w * 16 + l16] = c[r];
    }
}

// ---------------------------------------------------------------- kernel 2
// Barrier-free phase-2 K-loop: V LDS-resident (granule layout, stride-49),
// B direct global->VGPR (K-major granules, 1-deep prefetch).
__global__ __launch_bounds__(512, 4) void main_fused(
    const float* __restrict__ video, const float* __restrict__ bvid,
    const __bf16* __restrict__ wvid_k, const __bf16* __restrict__ wv_b,
    const float* __restrict__ Wh, const float* __restrict__ inter_g,
    float* __restrict__ out) {

    __shared__ uint4 pool4[3136];        // 50176 B: V granules, later vact rows
    __shared__ float inter_s[MDIM];
    __shared__ float z_s[MDIM];
    __shared__ float alpha_s[MDIM];
    __shared__ float content8[256];

    char* pool = (char*)pool4;

    const int bt   = blockIdx.x;
    const int tid  = threadIdx.x;
    const int w    = tid >> 6;
    const int lane = tid & 63;
    const int l16  = lane & 15;
    const int quad = lane >> 4;

    const float* Vg = video + (size_t)bt * (48 * 512);
    const char*  bbase = (const char*)wvid_k;

    // ---- phase 0
    if (tid < MDIM) { inter_s[tid] = inter_g[bt * MDIM + tid]; z_s[tid] = 0.f; }
    if (tid < 256) content8[tid] = 0.f;

    // ---- phase 1: V fp32 -> bf16 LDS granules (s,kc) at 16B-index kc*49+s
    #pragma unroll
    for (int p = 0; p < 6; ++p) {
        int g  = tid + p * 512;          // 3072 granules
        int s  = g >> 6;
        int kc = g & 63;
        const float4* s4 = (const float4*)(Vg + s * 512 + kc * 8);
        float4 x = s4[0], y = s4[1];
        bf16x8 gr = {(__bf16)x.x, (__bf16)x.y, (__bf16)x.z, (__bf16)x.w,
                     (__bf16)y.x, (__bf16)y.y, (__bf16)y.z, (__bf16)y.w};
        *(bf16x8*)(pool + (kc * 49 + s) * 16) = gr;
    }
    __syncthreads();

    // ---- phase 2: v = relu(V @ Wvid^T + b); wave w owns h in [64w, 64w+64)
    f32x4 acc[3][4];
    #pragma unroll
    for (int mt = 0; mt < 3; ++mt)
        #pragma unroll
        for (int j = 0; j < 4; ++j) {
            f32x4 z = {0.f, 0.f, 0.f, 0.f};
            acc[mt][j] = z;
        }
    {
        // B byte addr for (kt,j): (4kt+quad)*8192 + (w*64+j*16+l16)*16
        const int bIdx0 = quad * 8192 + (w * 64 + l16) * 16;
        bf16x8 bC[4];
        #pragma unroll
        for (int j = 0; j < 4; ++j)
            bC[j] = *(const bf16x8*)(bbase + bIdx0 + j * 256);

        #pragma unroll
        for (int kt = 0; kt < 16; ++kt) {
            bf16x8 bN[4];
            if (kt < 15) {
                #pragma unroll
                for (int j = 0; j < 4; ++j)
                    bN[j] = *(const bf16x8*)(bbase + bIdx0 + (kt + 1) * 32768 + j * 256);
            }
            bf16x8 a[3];
            #pragma unroll
            for (int mt = 0; mt < 3; ++mt)
                a[mt] = *(const bf16x8*)(pool + ((4 * kt + quad) * 49 + mt * 16 + l16) * 16);
            #pragma unroll
            for (int mt = 0; mt < 3; ++mt)
                #pragma unroll
                for (int j = 0; j < 4; ++j)
                    acc[mt][j] = __builtin_amdgcn_mfma_f32_16x16x32_bf16(
                                     a[mt], bC[j], acc[mt][j], 0, 0, 0);
            if (kt < 15) {
                #pragma unroll
                for (int j = 0; j < 4; ++j) bC[j] = bN[j];
            }
        }
    }
    __syncthreads();    // all phase-2 LDS reads done; pool reused for vact

    // epilogue: relu+bias -> vact rows of 1040 B. D: row(s)=quad*4+r, col(h)=l16
    #pragma unroll
    for (int j = 0; j < 4; ++j) {
        int h = w * 64 + j * 16 + l16;
        float bias = bvid[h];            // L2-hot scalar load
        #pragma unroll
        for (int mt = 0; mt < 3; ++mt) {
            #pragma unroll
            for (int r = 0; r < 4; ++r) {
                int s = mt * 16 + quad * 4 + r;
                *(__bf16*)(pool + s * 1040 + h * 2) =
                    (__bf16)fmaxf(acc[mt][j][r] + bias, 0.f);
            }
        }
    }
    __syncthreads();

    // ---- phase 3: content = vact @ Wv^T + inter; z[s] += tanh(.)*Wh[m]
    {
        int ti = w / 3, tj = w - ti * 3;    // tiles 0..7; tile 8 split below
        const __bf16* bp = wv_b + (size_t)(tj * 16 + l16) * 512 + quad * 8;
        const char*   ap = pool + (ti * 16 + l16) * 1040 + quad * 16;
        f32x4 c3 = {0.f, 0.f, 0.f, 0.f};
        bf16x8 aC = *(const bf16x8*)ap;
        bf16x8 bC = *(const bf16x8*)bp;
        #pragma unroll
        for (int kt = 0; kt < 16; ++kt) {
            bf16x8 aN, bN;
            if (kt < 15) {
                aN = *(const bf16x8*)(ap + (kt + 1) * 64);
                bN = *(const bf16x8*)(bp + (kt + 1) * 32);
            }
            c3 = __builtin_amdgcn_mfma_f32_16x16x32_bf16(aC, bC, c3, 0, 0, 0);
            if (kt < 15) { aC = aN; bC = bN; }
        }
        float wh = Wh[tj * 16 + l16];
        #pragma unroll
        for (int r = 0; r < 4; ++r) {
            int s = ti * 16 + quad * 4 + r;
            float contrib = tanhf(c3[r] + inter_s[s]) * wh;
            contrib += __shfl_xor(contrib, 1);
            contrib += __shfl_xor(contrib, 2);
            contrib += __shfl_xor(contrib, 4);
            contrib += __shfl_xor(contrib, 8);
            if (l16 == 0) atomicAdd(&z_s[s], contrib);
        }
        // tile 8 (ti=2,tj=2): wave w does kt = 2w, 2w+1
        f32x4 p8 = {0.f, 0.f, 0.f, 0.f};
        #pragma unroll
        for (int q = 0; q < 2; ++q) {
            int kt = 2 * w + q;
            bf16x8 a8 = *(const bf16x8*)(pool + (32 + l16) * 1040 + kt * 64 + quad * 16);
            bf16x8 b8 = *(const bf16x8*)(wv_b + (size_t)(32 + l16) * 512 + kt * 32 + quad * 8);
            p8 = __builtin_amdgcn_mfma_f32_16x16x32_bf16(a8, b8, p8, 0, 0, 0);
        }
        #pragma unroll
        for (int r = 0; r < 4; ++r)
            atomicAdd(&content8[(quad * 4 + r) * 16 + l16], p8[r]);
    }
    __syncthreads();

    if (w == 0) {
        float wh = Wh[32 + l16];
        #pragma unroll
        for (int r = 0; r < 4; ++r) {
            int s = 32 + quad * 4 + r;
            float contrib = tanhf(content8[(quad * 4 + r) * 16 + l16] + inter_s[s]) * wh;
            contrib += __shfl_xor(contrib, 1);
            contrib += __shfl_xor(contrib, 2);
            contrib += __shfl_xor(contrib, 4);
            contrib += __shfl_xor(contrib, 8);
            if (l16 == 0) atomicAdd(&z_s[s], contrib);
        }
    }
    __syncthreads();

    // ---- phase 4: softmax over z[48] (wave 0)
    if (w == 0) {
        float x = (lane < MDIM) ? z_s[lane] : -INFINITY;
        float mx = x;
        #pragma unroll
        for (int off = 32; off >= 1; off >>= 1) mx = fmaxf(mx, __shfl_xor(mx, off));
        float e = (lane < MDIM) ? expf(x - mx) : 0.f;
        float sm = e;
        #pragma unroll
        for (int off = 32; off >= 1; off >>= 1) sm += __shfl_xor(sm, off);
        if (lane < MDIM) alpha_s[lane] = e / sm;
    }
    __syncthreads();

    // ---- phase 5: c[h] = sum_s alpha[s] * V[s][h] (fp32 global, L2/L3-hot)
    float acc5 = 0.f;
    #pragma unroll
    for (int s = 0; s < MDIM; ++s)
        acc5 += alpha_s[s] * Vg[s * 512 + tid];
    out[(size_t)bt * 512 + tid] = acc5;
}

// ---------------------------------------------------------------- launch
extern "C" void kernel_launch(void* const* d_in, const int* in_sizes, int n_in,
                              void* d_out, int out_size, void* d_ws, size_t ws_size,
                              hipStream_t stream) {
    const float* audio   = (const float*)d_in[0];
    const float* video   = (const float*)d_in[1];
    const float* W_audio = (const float*)d_in[2];
    const float* b_audio = (const float*)d_in[3];
    const float* W_video = (const float*)d_in[4];
    const float* b_video = (const float*)d_in[5];
    const float* W_v     = (const float*)d_in[6];
    const float* W_g     = (const float*)d_in[7];
    const float* W_h     = (const float*)d_in[8];
    float* out = (float*)d_out;

    char* ws = (char*)d_ws;
    __bf16* wvid_k = (__bf16*)(ws + WS_WVID);
    __bf16* wv_b   = (__bf16*)(ws + WS_WV);
    __bf16* wg_b   = (__bf16*)(ws + WS_WG);
    float*  inter  = (float*)(ws + WS_INTER);

    convert_weights<<<304, 256, 0, stream>>>(W_video, W_v, W_g, wvid_k, wv_b, wg_b);
    audio_batch<<<BT / 16, 512, 0, stream>>>(audio, W_audio, b_audio, wg_b, inter);
    main_fused<<<BT, 512, 0, stream>>>(video, b_video, wvid_k, wv_b, W_h, inter, out);
}